// Round 1
// baseline (9.741 us; speedup 1.0000x reference)
//
#include <hip/hip_runtime.h>
#include <hip/hip_bf16.h>

// Only tokens[0,0,0:10] survive the reference's reshape(-1)[:10].
// tokens[0,0,k] = sum_d patches[0,0,d] * W[k,d]
// patches[0,0,d] = images[0, c, ph, pw], d = c*256 + ph*16 + pw  (ps=16)
// Then softmax over the 10 values.

__global__ __launch_bounds__(640) void vit_head_kernel(
    const float* __restrict__ images,  // [256,3,224,224]
    const float* __restrict__ W,       // [768,768]
    float* __restrict__ out)           // [10]
{
    __shared__ float patch[768];
    __shared__ float dots[10];

    const int tid = threadIdx.x;           // 640 threads = 10 waves
    // Stage patch (0,0) of image 0 into LDS.
    for (int d = tid; d < 768; d += 640) {
        const int c  = d >> 8;             // 0..2
        const int ph = (d >> 4) & 15;      // 0..15
        const int pw = d & 15;             // 0..15
        patch[d] = images[c * 50176 + ph * 224 + pw];  // 50176 = 224*224
    }
    __syncthreads();

    const int k    = tid >> 6;             // wave id = class 0..9
    const int lane = tid & 63;

    float sum = 0.0f;
    const float* __restrict__ wk = W + k * 768;
    #pragma unroll
    for (int d0 = 0; d0 < 768; d0 += 64)
        sum += patch[d0 + lane] * wk[d0 + lane];

    // wave64 reduce
    #pragma unroll
    for (int off = 32; off > 0; off >>= 1)
        sum += __shfl_down(sum, off, 64);
    if (lane == 0) dots[k] = sum;
    __syncthreads();

    if (tid == 0) {
        float m = dots[0];
        #pragma unroll
        for (int i = 1; i < 10; ++i) m = fmaxf(m, dots[i]);
        float e[10];
        float s = 0.0f;
        #pragma unroll
        for (int i = 0; i < 10; ++i) { e[i] = __expf(dots[i] - m); s += e[i]; }
        const float inv = 1.0f / s;
        #pragma unroll
        for (int i = 0; i < 10; ++i) out[i] = e[i] * inv;
    }
}

extern "C" void kernel_launch(void* const* d_in, const int* in_sizes, int n_in,
                              void* d_out, int out_size, void* d_ws, size_t ws_size,
                              hipStream_t stream) {
    const float* images = (const float*)d_in[0];
    const float* W      = (const float*)d_in[1];
    float* out          = (float*)d_out;
    vit_head_kernel<<<1, 640, 0, stream>>>(images, W, out);
}

// Round 2
// 9.652 us; speedup vs baseline: 1.0092x; 1.0092x over previous
//
#include <hip/hip_runtime.h>
#include <hip/hip_bf16.h>

// Only tokens[0,0,0:10] survive the reference's reshape(-1)[:10].
// tokens[0,0,k] = sum_d patch[d] * W[k,d],  patch[d] = images[0, c, ph, pw],
// d = c*256 + ph*16 + pw (ps=16). Then softmax over the 10 scalars.
//
// Single-wave, zero-LDS, zero-barrier variant: minimize the latency chain.
// Each lane holds 12 patch elems in regs; 10 dots via __shfl_xor butterfly.

__global__ __launch_bounds__(64) void vit_head_wave(
    const float* __restrict__ images,  // [256,3,224,224]
    const float* __restrict__ W,       // [768,768]
    float* __restrict__ out)           // [10]
{
    const int lane = threadIdx.x;      // 0..63, one wave

    // Patch (0,0) of image 0: lane's 12 elements, d = lane + 64*j.
    float p[12];
    #pragma unroll
    for (int j = 0; j < 12; ++j) {
        const int d  = lane + 64 * j;
        const int c  = d >> 8;
        const int ph = (d >> 4) & 15;
        const int pw = d & 15;
        p[j] = images[c * 50176 + ph * 224 + pw];  // 50176 = 224*224
    }

    float dot[10];
    #pragma unroll
    for (int k = 0; k < 10; ++k) {
        float s = 0.0f;
        const float* __restrict__ wk = W + k * 768;
        #pragma unroll
        for (int j = 0; j < 12; ++j)
            s += p[j] * wk[lane + 64 * j];
        // butterfly reduce across the wave (all lanes end with the sum)
        #pragma unroll
        for (int off = 32; off > 0; off >>= 1)
            s += __shfl_xor(s, off, 64);
        dot[k] = s;
    }

    if (lane == 0) {
        float m = dot[0];
        #pragma unroll
        for (int i = 1; i < 10; ++i) m = fmaxf(m, dot[i]);
        float e[10];
        float ssum = 0.0f;
        #pragma unroll
        for (int i = 0; i < 10; ++i) { e[i] = __expf(dot[i] - m); ssum += e[i]; }
        const float inv = 1.0f / ssum;
        #pragma unroll
        for (int i = 0; i < 10; ++i) out[i] = e[i] * inv;
    }
}

extern "C" void kernel_launch(void* const* d_in, const int* in_sizes, int n_in,
                              void* d_out, int out_size, void* d_ws, size_t ws_size,
                              hipStream_t stream) {
    const float* images = (const float*)d_in[0];
    const float* W      = (const float*)d_in[1];
    float* out          = (float*)d_out;
    vit_head_wave<<<1, 64, 0, stream>>>(images, W, out);
}